// Round 11
// baseline (414.924 us; speedup 1.0000x reference)
//
#include <hip/hip_runtime.h>
#include <hip/hip_fp16.h>
#include <cstdint>
#include <cstddef>

#define NHEADS 4
#define OUT_C 32
#define HC 128          // NHEADS*OUT_C
#define IN_CH 128
#define NEG_SLOPE 0.2f
#define LDSPAD 136      // halves per LDS row (128 + 8 pad)
#define KEDGE 4096      // edges per bscatter block (16/thread)
#define WLP 133         // W_lin LDS row pitch (floats): 133*4B -> lane o -> bank o*5%32, all distinct

typedef _Float16 half8 __attribute__((ext_vector_type(8)));
typedef float floatx4 __attribute__((ext_vector_type(4)));

static inline size_t align256(size_t v) { return (v + 255) & ~(size_t)255; }

__device__ __forceinline__ float lrelu(float v) { return v > 0.f ? v : NEG_SLOPE * v; }

__device__ __forceinline__ float wred_sum(float v) {
    v += __shfl_xor(v, 1);
    v += __shfl_xor(v, 2);
    v += __shfl_xor(v, 4);
    v += __shfl_xor(v, 8);
    v += __shfl_xor(v, 16);
    v += __shfl_xor(v, 32);
    return v;
}

__device__ __forceinline__ unsigned int pack_h2(float a, float b) {
    __half2 h = __floats2half2_rn(a, b);
    return *reinterpret_cast<unsigned int*>(&h);
}
__device__ __forceinline__ float2 unpack_h2(unsigned int u) {
    __half2 h = *reinterpret_cast<__half2*>(&u);
    return __half22float2(h);
}

// Block-level int64-vs-int32 edge dtype detect (odd words zero => int64).
__device__ __forceinline__ int detect_f64(const int* __restrict__ ei, int E, int* sf) {
    int t = threadIdx.x;
    if (t == 0) *sf = 0;
    __syncthreads();
    int lim = E < 1024 ? E : 1024;
    int acc = 0;
    for (int i = t; i < lim; i += 256) acc |= ei[2 * i + 1];
    acc |= __shfl_xor(acc, 1);
    acc |= __shfl_xor(acc, 2);
    acc |= __shfl_xor(acc, 4);
    acc |= __shfl_xor(acc, 8);
    acc |= __shfl_xor(acc, 16);
    acc |= __shfl_xor(acc, 32);
    if ((t & 63) == 0 && acc) atomicOr(sf, 1);
    __syncthreads();
    return *sf == 0;
}

// ---------------------------------------------------------------------------
// Fused kernel: blocks [0,GB) run the MFMA GEMM producing h (fp16) + attention
// logits; blocks [GB, GB+NBH) run the bucket histogram (independent work that
// overlaps the MFMA phase's latency bubbles).
__global__ __launch_bounds__(256) void gemm_hist(const float* __restrict__ x,
                                                 const float* __restrict__ W,
                                                 const float* __restrict__ att_src,
                                                 const float* __restrict__ att_dst,
                                                 __half* __restrict__ h,
                                                 float* __restrict__ a_src,
                                                 float* __restrict__ a_dst, int n,
                                                 const int* __restrict__ ei,
                                                 int* __restrict__ bcount,
                                                 int E, int sh, int GB) {
    __shared__ __align__(16) _Float16 Ws[128 * LDSPAD];
    __shared__ __align__(16) _Float16 Xs[128 * LDSPAD];   // reused as h-tile
    __shared__ int hc[256];
    __shared__ int sf;
    int tid = threadIdx.x;

    if (blockIdx.x >= GB) {
        // ---------------- bucket histogram part ----------------
        hc[tid] = 0;
        int f64 = detect_f64(ei, E, &sf);   // includes syncthreads
        int nbh = gridDim.x - GB;
        int stride = nbh * 256;
        for (int i = (blockIdx.x - GB) * 256 + tid; i < E; i += stride) {
            int d;
            if (f64) d = (int)((const long long*)ei)[(size_t)E + i];
            else     d = ei[(size_t)E + i];
            atomicAdd(&hc[d >> sh], 1);
        }
        __syncthreads();
        if (hc[tid]) atomicAdd(&bcount[tid], hc[tid]);
        return;
    }
    // ---------------- GEMM part ----------------
    int rowbase = blockIdx.x << 7;

    // stage W with fp32->fp16 conversion (4096 float4)
    const float4* wf = (const float4*)W;
#pragma unroll
    for (int i = 0; i < 16; ++i) {
        int u = (i << 8) + tid;
        int r = u >> 5, g = u & 31;
        float4 v = wf[u];
        uint2 uu;
        uu.x = pack_h2(v.x, v.y);
        uu.y = pack_h2(v.z, v.w);
        *(uint2*)&Ws[r * LDSPAD + (g << 2)] = uu;
    }
    const float4* x4 = (const float4*)x;
#pragma unroll
    for (int i = 0; i < 16; ++i) {
        int u = (i << 8) + tid;
        int r = u >> 5, c4 = u & 31;
        int row = rowbase + r;
        if (row >= n) row = n - 1;
        float4 v = x4[((size_t)row << 5) + c4];
        uint2 uu;
        uu.x = pack_h2(v.x, v.y);
        uu.y = pack_h2(v.z, v.w);
        *(uint2*)&Xs[r * LDSPAD + (c4 << 2)] = uu;
    }
    __syncthreads();

    int lane = tid & 63, w = tid >> 6;
    int quad = lane >> 4, Lm = lane & 15;
    floatx4 acc[2][8];
#pragma unroll
    for (int rt = 0; rt < 2; ++rt)
#pragma unroll
        for (int c = 0; c < 8; ++c) acc[rt][c] = (floatx4){0.f, 0.f, 0.f, 0.f};

#pragma unroll
    for (int kc = 0; kc < 128; kc += 32) {
        int ko = kc + (quad << 3);
        half8 a0 = *(const half8*)&Xs[((w << 5) + Lm) * LDSPAD + ko];
        half8 a1 = *(const half8*)&Xs[((w << 5) + 16 + Lm) * LDSPAD + ko];
#pragma unroll
        for (int c = 0; c < 8; ++c) {
            half8 b = *(const half8*)&Ws[((c << 4) + Lm) * LDSPAD + ko];
            acc[0][c] = __builtin_amdgcn_mfma_f32_16x16x32_f16(a0, b, acc[0][c], 0, 0, 0);
            acc[1][c] = __builtin_amdgcn_mfma_f32_16x16x32_f16(a1, b, acc[1][c], 0, 0, 0);
        }
    }
    __syncthreads();
#pragma unroll
    for (int rt = 0; rt < 2; ++rt)
#pragma unroll
        for (int c = 0; c < 8; ++c)
#pragma unroll
            for (int i = 0; i < 4; ++i) {
                int rl = (w << 5) + (rt << 4) + (quad << 2) + i;
                int cl = (c << 4) + Lm;
                Xs[rl * LDSPAD + cl] = (_Float16)acc[rt][c][i];
            }
    __syncthreads();
    // coalesced interleaved h store
#pragma unroll
    for (int i = 0; i < 8; ++i) {
        int u = (i << 8) + tid;
        int r = u >> 4, g = u & 15;
        int row = rowbase + r;
        if (row < n) {
            uint4 v = *(uint4*)&Xs[r * LDSPAD + (g << 3)];
            *(uint4*)(h + ((size_t)row << 7) + (g << 3)) = v;
        }
    }
    // attention logits: thread covers row r=tid>>1, cols seg*64..+63
    int r = tid >> 1, seg = tid & 1;
    int row = rowbase + r;
    const _Float16* hp = &Xs[r * LDSPAD + (seg << 6)];
    float sa = 0.f, da = 0.f, sb = 0.f, db = 0.f;
#pragma unroll
    for (int g8 = 0; g8 < 8; ++g8) {
        half8 v = *(const half8*)&hp[g8 << 3];
        int co = (seg << 6) + (g8 << 3);
        float4 A1 = *(const float4*)&att_src[co];
        float4 A2 = *(const float4*)&att_src[co + 4];
        float4 D1 = *(const float4*)&att_dst[co];
        float4 D2 = *(const float4*)&att_dst[co + 4];
        float f0 = (float)v[0], f1 = (float)v[1], f2 = (float)v[2], f3 = (float)v[3];
        float f4 = (float)v[4], f5 = (float)v[5], f6 = (float)v[6], f7 = (float)v[7];
        float ts = f0 * A1.x + f1 * A1.y + f2 * A1.z + f3 * A1.w
                 + f4 * A2.x + f5 * A2.y + f6 * A2.z + f7 * A2.w;
        float td = f0 * D1.x + f1 * D1.y + f2 * D1.z + f3 * D1.w
                 + f4 * D2.x + f5 * D2.y + f6 * D2.z + f7 * D2.w;
        if (g8 < 4) { sa += ts; da += td; } else { sb += ts; db += td; }
    }
    if (row < n) {
        int base = (row << 2) + (seg << 1);
        a_src[base] = sa;
        a_src[base + 1] = sb;
        a_dst[base] = da;
        a_dst[base + 1] = db;
    }
}

// ---------------------------------------------------------------------------
// Pass A: bucket scatter with local bucket-base scan. (dst,src) grouped by
// bucket -> single writer block per 64B line.
__global__ __launch_bounds__(256) void bscatter(const int* __restrict__ ei,
                                                const int* __restrict__ bcount,
                                                int* __restrict__ gcursor,
                                                int2* __restrict__ bkt,
                                                int E, int n, int sh) {
    __shared__ int cnt[256], base[256], lcur[256], ts[256];
    __shared__ int sf;
    int t = threadIdx.x;
    cnt[t] = 0;
    lcur[t] = 0;
    int f64 = detect_f64(ei, E, &sf);   // includes syncthreads
    int total = E + n;
    int i0 = blockIdx.x * KEDGE;
    int ed[16], es[16];
#pragma unroll
    for (int j = 0; j < 16; ++j) {
        int i = i0 + (j << 8) + t;
        int s = 0, d = -1;
        if (i < total) {
            if (i < E) {
                if (f64) {
                    s = (int)((const long long*)ei)[i];
                    d = (int)((const long long*)ei)[(size_t)E + i];
                } else {
                    s = ei[i];
                    d = ei[(size_t)E + i];
                }
            } else {
                s = d = i - E;
            }
            atomicAdd(&cnt[d >> sh], 1);
        }
        ed[j] = d;
        es[j] = s;
    }
    // bucket-base scan (bcount + analytic self-loops)
    int lo = t << sh, hi = (t + 1) << sh;
    if (hi > n) hi = n;
    int nodes = hi > lo ? hi - lo : 0;
    int v = bcount[t] + nodes;
    ts[t] = v;
    __syncthreads();
    int run = v;
    for (int d = 1; d < 256; d <<= 1) {
        int o = (t >= d) ? ts[t - d] : 0;
        __syncthreads();
        run += o;
        ts[t] = run;
        __syncthreads();
    }
    int excl = run - v;
    base[t] = excl + (cnt[t] ? atomicAdd(&gcursor[t], cnt[t]) : 0);
    __syncthreads();
#pragma unroll
    for (int j = 0; j < 16; ++j) {
        int d = ed[j];
        if (d >= 0) {
            int b = d >> sh;
            int pos = base[b] + atomicAdd(&lcur[b], 1);
            bkt[pos] = make_int2(d, es[j]);
        }
    }
}

// ---------------------------------------------------------------------------
// Pass B: one block per bucket. Local bucket-base scan, per-node histogram +
// block scan (emits off[]) + in-bucket scatter (L2-local writes).
__global__ __launch_bounds__(256) void bsort(const int2* __restrict__ bkt,
                                             const int* __restrict__ bcount,
                                             int* __restrict__ off,
                                             int* __restrict__ sorted,
                                             int n, int E, int sh) {
    __shared__ int cnt[512], offl[512], ts[256];
    int t = threadIdx.x, bid = blockIdx.x;
    int lo = t << sh, hi = (t + 1) << sh;
    if (hi > n) hi = n;
    int nodes = hi > lo ? hi - lo : 0;
    int v = bcount[t] + nodes;
    ts[t] = v;
    __syncthreads();
    int run = v;
    for (int d = 1; d < 256; d <<= 1) {
        int o = (t >= d) ? ts[t - d] : 0;
        __syncthreads();
        run += o;
        ts[t] = run;
        __syncthreads();
    }
    int e0 = (bid > 0) ? ts[bid - 1] : 0;
    int e1 = ts[bid];
    if (bid == gridDim.x - 1 && t == 0) off[n] = E + n;
    int node0 = bid << sh;
    int node1 = (bid + 1) << sh;
    if (node1 > n) node1 = n;
    int nn = node1 - node0;
    __syncthreads();
    cnt[t] = 0;
    cnt[t + 256] = 0;
    __syncthreads();
    for (int i = e0 + t; i < e1; i += 256) {
        int2 e = bkt[i];
        atomicAdd(&cnt[e.x - node0], 1);
    }
    __syncthreads();
    int a = cnt[t << 1], b = cnt[(t << 1) + 1];
    int s = a + b;
    ts[t] = s;
    __syncthreads();
    run = s;
    for (int d = 1; d < 256; d <<= 1) {
        int o = (t >= d) ? ts[t - d] : 0;
        __syncthreads();
        run += o;
        ts[t] = run;
        __syncthreads();
    }
    int excl = run - s;
    offl[t << 1] = excl;
    offl[(t << 1) + 1] = excl + a;
    cnt[t << 1] = 0;
    cnt[(t << 1) + 1] = 0;
    __syncthreads();
    for (int i = t; i < nn; i += 256) off[node0 + i] = e0 + offl[i];
    for (int i = e0 + t; i < e1; i += 256) {
        int2 e = bkt[i];
        int li = e.x - node0;
        int pos = e0 + offl[li] + atomicAdd(&cnt[li], 1);
        sorted[pos] = e.y;
    }
}

// ---------------------------------------------------------------------------
// Gather-accumulate (fp16 h, interleaved), half-wave owns 128ch: lane L owns
// ch 4L..4L+3 (8B/edge). Edges j = half, half+2, ...; 8 gathers in flight.
__device__ __forceinline__ void accum_half(const int* ssrc, const float* sal,
                                           const __half* __restrict__ h,
                                           int deg, int half, int L, int head,
                                           float4& acc) {
    float4 a0 = {0, 0, 0, 0}, a1 = {0, 0, 0, 0}, a2 = {0, 0, 0, 0}, a3 = {0, 0, 0, 0};
    int j = half;
    for (; j + 14 < deg; j += 16) {
        int s0 = ssrc[j], s1 = ssrc[j + 2], s2 = ssrc[j + 4], s3 = ssrc[j + 6];
        int s4 = ssrc[j + 8], s5 = ssrc[j + 10], s6 = ssrc[j + 12], s7 = ssrc[j + 14];
        float w0 = sal[(j << 2) + head];
        float w1 = sal[((j + 2) << 2) + head];
        float w2 = sal[((j + 4) << 2) + head];
        float w3 = sal[((j + 6) << 2) + head];
        float w4 = sal[((j + 8) << 2) + head];
        float w5 = sal[((j + 10) << 2) + head];
        float w6 = sal[((j + 12) << 2) + head];
        float w7 = sal[((j + 14) << 2) + head];
        uint2 u0 = *(const uint2*)(h + ((size_t)s0 << 7) + (L << 2));
        uint2 u1 = *(const uint2*)(h + ((size_t)s1 << 7) + (L << 2));
        uint2 u2 = *(const uint2*)(h + ((size_t)s2 << 7) + (L << 2));
        uint2 u3 = *(const uint2*)(h + ((size_t)s3 << 7) + (L << 2));
        uint2 u4 = *(const uint2*)(h + ((size_t)s4 << 7) + (L << 2));
        uint2 u5 = *(const uint2*)(h + ((size_t)s5 << 7) + (L << 2));
        uint2 u6 = *(const uint2*)(h + ((size_t)s6 << 7) + (L << 2));
        uint2 u7 = *(const uint2*)(h + ((size_t)s7 << 7) + (L << 2));
        float2 fa, fb;
        fa = unpack_h2(u0.x); fb = unpack_h2(u0.y);
        a0.x = fmaf(w0, fa.x, a0.x); a0.y = fmaf(w0, fa.y, a0.y);
        a0.z = fmaf(w0, fb.x, a0.z); a0.w = fmaf(w0, fb.y, a0.w);
        fa = unpack_h2(u1.x); fb = unpack_h2(u1.y);
        a1.x = fmaf(w1, fa.x, a1.x); a1.y = fmaf(w1, fa.y, a1.y);
        a1.z = fmaf(w1, fb.x, a1.z); a1.w = fmaf(w1, fb.y, a1.w);
        fa = unpack_h2(u2.x); fb = unpack_h2(u2.y);
        a2.x = fmaf(w2, fa.x, a2.x); a2.y = fmaf(w2, fa.y, a2.y);
        a2.z = fmaf(w2, fb.x, a2.z); a2.w = fmaf(w2, fb.y, a2.w);
        fa = unpack_h2(u3.x); fb = unpack_h2(u3.y);
        a3.x = fmaf(w3, fa.x, a3.x); a3.y = fmaf(w3, fa.y, a3.y);
        a3.z = fmaf(w3, fb.x, a3.z); a3.w = fmaf(w3, fb.y, a3.w);
        fa = unpack_h2(u4.x); fb = unpack_h2(u4.y);
        a0.x = fmaf(w4, fa.x, a0.x); a0.y = fmaf(w4, fa.y, a0.y);
        a0.z = fmaf(w4, fb.x, a0.z); a0.w = fmaf(w4, fb.y, a0.w);
        fa = unpack_h2(u5.x); fb = unpack_h2(u5.y);
        a1.x = fmaf(w5, fa.x, a1.x); a1.y = fmaf(w5, fa.y, a1.y);
        a1.z = fmaf(w5, fb.x, a1.z); a1.w = fmaf(w5, fb.y, a1.w);
        fa = unpack_h2(u6.x); fb = unpack_h2(u6.y);
        a2.x = fmaf(w6, fa.x, a2.x); a2.y = fmaf(w6, fa.y, a2.y);
        a2.z = fmaf(w6, fb.x, a2.z); a2.w = fmaf(w6, fb.y, a2.w);
        fa = unpack_h2(u7.x); fb = unpack_h2(u7.y);
        a3.x = fmaf(w7, fa.x, a3.x); a3.y = fmaf(w7, fa.y, a3.y);
        a3.z = fmaf(w7, fb.x, a3.z); a3.w = fmaf(w7, fb.y, a3.w);
    }
    for (; j + 6 < deg; j += 8) {
        int s0 = ssrc[j], s1 = ssrc[j + 2], s2 = ssrc[j + 4], s3 = ssrc[j + 6];
        float w0 = sal[(j << 2) + head];
        float w1 = sal[((j + 2) << 2) + head];
        float w2 = sal[((j + 4) << 2) + head];
        float w3 = sal[((j + 6) << 2) + head];
        uint2 u0 = *(const uint2*)(h + ((size_t)s0 << 7) + (L << 2));
        uint2 u1 = *(const uint2*)(h + ((size_t)s1 << 7) + (L << 2));
        uint2 u2 = *(const uint2*)(h + ((size_t)s2 << 7) + (L << 2));
        uint2 u3 = *(const uint2*)(h + ((size_t)s3 << 7) + (L << 2));
        float2 fa, fb;
        fa = unpack_h2(u0.x); fb = unpack_h2(u0.y);
        a0.x = fmaf(w0, fa.x, a0.x); a0.y = fmaf(w0, fa.y, a0.y);
        a0.z = fmaf(w0, fb.x, a0.z); a0.w = fmaf(w0, fb.y, a0.w);
        fa = unpack_h2(u1.x); fb = unpack_h2(u1.y);
        a1.x = fmaf(w1, fa.x, a1.x); a1.y = fmaf(w1, fa.y, a1.y);
        a1.z = fmaf(w1, fb.x, a1.z); a1.w = fmaf(w1, fb.y, a1.w);
        fa = unpack_h2(u2.x); fb = unpack_h2(u2.y);
        a2.x = fmaf(w2, fa.x, a2.x); a2.y = fmaf(w2, fa.y, a2.y);
        a2.z = fmaf(w2, fb.x, a2.z); a2.w = fmaf(w2, fb.y, a2.w);
        fa = unpack_h2(u3.x); fb = unpack_h2(u3.y);
        a3.x = fmaf(w3, fa.x, a3.x); a3.y = fmaf(w3, fa.y, a3.y);
        a3.z = fmaf(w3, fb.x, a3.z); a3.w = fmaf(w3, fb.y, a3.w);
    }
    for (; j < deg; j += 2) {
        int s0 = ssrc[j];
        float w0 = sal[(j << 2) + head];
        uint2 u0 = *(const uint2*)(h + ((size_t)s0 << 7) + (L << 2));
        float2 fa = unpack_h2(u0.x), fb = unpack_h2(u0.y);
        a0.x = fmaf(w0, fa.x, a0.x); a0.y = fmaf(w0, fa.y, a0.y);
        a0.z = fmaf(w0, fb.x, a0.z); a0.w = fmaf(w0, fb.y, a0.w);
    }
    acc.x += (a0.x + a1.x) + (a2.x + a3.x);
    acc.y += (a0.y + a1.y) + (a2.y + a3.y);
    acc.z += (a0.z + a1.z) + (a2.z + a3.z);
    acc.w += (a0.w + a1.w) + (a2.w + a3.w);
}

// One wave per destination node, with FUSED final projection + ELU.
// Staging: lane-per-edge src read + a_src gather + alpha=exp(lrelu(.)) fp32
// -> LDS. Gather-accumulate. Epilogue: normalize in fp32, per-wave LDS
// broadcast of the 128-ch row, each lane dots its half of W_lin row o=lane&31,
// cross-half combine, ELU, direct out write. (proj kernel eliminated.)
__global__ __launch_bounds__(256) void aggregate(const __half* __restrict__ h,
                                                 const int* __restrict__ sorted,
                                                 const int* __restrict__ off,
                                                 const float* __restrict__ a_src,
                                                 const float* __restrict__ a_dst,
                                                 const float* __restrict__ bias,
                                                 const float* __restrict__ W_lin,
                                                 const float* __restrict__ b_lin,
                                                 float* __restrict__ out, int n) {
    __shared__ __align__(16) int sh_src[4][64];
    __shared__ __align__(16) float sh_al[4][256];    // [edge][head]
    __shared__ __align__(16) float sh_res[4][128];   // per-wave agg row
    __shared__ __align__(16) float Wl[32 * WLP];     // W_lin[o][k], pitch 133
    __shared__ float sbl[32];
    int tid = threadIdx.x;
    // stage W_lin + b_lin
    for (int i = tid; i < 4096; i += 256) {
        int o = i >> 7, k = i & 127;
        Wl[o * WLP + k] = W_lin[i];
    }
    if (tid < 32) sbl[tid] = b_lin[tid];
    __syncthreads();

    int wslot = tid >> 6;
    int lane = tid & 63;
    int wid = blockIdx.x * 4 + wslot;
    int nw = gridDim.x * 4;
    int L = lane & 31, half = lane >> 5, head = L >> 3;
    float4 b4 = ((const float4*)bias)[L];
    const float4* as4 = (const float4*)a_src;
    const float4* ad4 = (const float4*)a_dst;
    int* ssrc = sh_src[wslot];
    float* sal = sh_al[wslot];
    float* sres = sh_res[wslot];
    const float* wrow = &Wl[L * WLP + (half << 6)];
    const float* rrow = &sres[half << 6];

    for (int node = wid; node < n; node += nw) {
        int start = off[node], end = off[node + 1];
        int deg = end - start;          // >= 1 (self loop)
        float4 ad = ad4[node];
        float4 acc = {0.f, 0.f, 0.f, 0.f};
        float4 psum = {0.f, 0.f, 0.f, 0.f};

        if (deg <= 64) {
            bool v = lane < deg;
            int idx = start + (v ? lane : 0);
            int s = sorted[idx];
            float4 as = as4[s];
            float4 p;
            p.x = v ? __expf(lrelu(as.x + ad.x)) : 0.f;
            p.y = v ? __expf(lrelu(as.y + ad.y)) : 0.f;
            p.z = v ? __expf(lrelu(as.z + ad.z)) : 0.f;
            p.w = v ? __expf(lrelu(as.w + ad.w)) : 0.f;
            psum = p;
            ssrc[lane] = s;
            *(float4*)&sal[lane << 2] = p;
            asm volatile("s_waitcnt lgkmcnt(0)" ::: "memory");
            accum_half(ssrc, sal, h, deg, half, L, head, acc);
            asm volatile("" ::: "memory");
        } else {
            // chunked path (rare)
            for (int bb = 0; bb < deg; bb += 64) {
                int i = bb + lane;
                bool v = i < deg;
                int idx = start + (v ? i : 0);
                int s = sorted[idx];
                float4 as = as4[s];
                float4 p;
                p.x = v ? __expf(lrelu(as.x + ad.x)) : 0.f;
                p.y = v ? __expf(lrelu(as.y + ad.y)) : 0.f;
                p.z = v ? __expf(lrelu(as.z + ad.z)) : 0.f;
                p.w = v ? __expf(lrelu(as.w + ad.w)) : 0.f;
                psum.x += p.x; psum.y += p.y; psum.z += p.z; psum.w += p.w;
                ssrc[lane] = s;
                *(float4*)&sal[lane << 2] = p;
                asm volatile("s_waitcnt lgkmcnt(0)" ::: "memory");
                int cl = deg - bb;
                if (cl > 64) cl = 64;
                accum_half(ssrc, sal, h, cl, half, L, head, acc);
                asm volatile("" ::: "memory");
            }
        }
        float s0 = wred_sum(psum.x), s1 = wred_sum(psum.y);
        float s2 = wred_sum(psum.z), s3 = wred_sum(psum.w);
        float sh = (head == 0) ? s0 : (head == 1) ? s1 : (head == 2) ? s2 : s3;
        float inv = 1.f / sh;
        acc.x += __shfl_xor(acc.x, 32);
        acc.y += __shfl_xor(acc.y, 32);
        acc.z += __shfl_xor(acc.z, 32);
        acc.w += __shfl_xor(acc.w, 32);
        if (lane < 32) {
            float4 res = {fmaf(acc.x, inv, b4.x), fmaf(acc.y, inv, b4.y),
                          fmaf(acc.z, inv, b4.z), fmaf(acc.w, inv, b4.w)};
            *(float4*)&sres[L << 2] = res;   // fp32, no fp16 roundtrip
        }
        asm volatile("s_waitcnt lgkmcnt(0)" ::: "memory");
        // fused projection: output o = L, k-half = half
        float sum = 0.f;
#pragma unroll
        for (int k4 = 0; k4 < 64; k4 += 8) {
            float4 r1 = *(const float4*)&rrow[k4];
            float4 r2 = *(const float4*)&rrow[k4 + 4];
            float4 w1 = *(const float4*)&wrow[k4];
            float4 w2 = *(const float4*)&wrow[k4 + 4];
            sum = fmaf(r1.x, w1.x, sum);
            sum = fmaf(r1.y, w1.y, sum);
            sum = fmaf(r1.z, w1.z, sum);
            sum = fmaf(r1.w, w1.w, sum);
            sum = fmaf(r2.x, w2.x, sum);
            sum = fmaf(r2.y, w2.y, sum);
            sum = fmaf(r2.z, w2.z, sum);
            sum = fmaf(r2.w, w2.w, sum);
        }
        sum += __shfl_xor(sum, 32);
        if (lane < 32) {
            float v = sum + sbl[L];
            out[(size_t)node * 32 + L] = v > 0.f ? v : __expf(v) - 1.f;
        }
        asm volatile("" ::: "memory");   // sres must not be overwritten early
    }
}

// ---------------------------------------------------------------------------
extern "C" void kernel_launch(void* const* d_in, const int* in_sizes, int n_in,
                              void* d_out, int out_size, void* d_ws, size_t ws_size,
                              hipStream_t stream) {
    const float* x = (const float*)d_in[0];
    const int* ei = (const int*)d_in[1];
    const float* W = (const float*)d_in[2];
    const float* att_src = (const float*)d_in[3];
    const float* att_dst = (const float*)d_in[4];
    const float* bias_conv = (const float*)d_in[5];
    const float* W_lin = (const float*)d_in[6];
    const float* b_lin = (const float*)d_in[7];
    int n = in_sizes[0] / IN_CH;
    int E = in_sizes[1] / 2;

    int sh = 0;
    while (((n + (1 << sh) - 1) >> sh) > 256) sh++;
    int NB = (n + (1 << sh) - 1) >> sh;

    char* ws = (char*)d_ws;
    size_t o = 0;
    auto alloc = [&](size_t bytes) { char* p = ws + o; o = align256(o + bytes); return p; };
    __half* h      = (__half*)alloc((size_t)n * HC * 2);
    float* a_src   = (float*)alloc((size_t)n * NHEADS * 4);
    float* a_dst   = (float*)alloc((size_t)n * NHEADS * 4);
    int* off       = (int*)alloc(((size_t)n + 1) * 4);
    int* bcount    = (int*)alloc(256 * 4);
    int* gcursor   = (int*)alloc(256 * 4);
    int* sorted    = (int*)alloc((size_t)(E + n + 64) * 4);
    int2* bkt      = (int2*)alloc((size_t)(E + n + 64) * 8);

    // bcount and gcursor are adjacent: one memset covers both
    hipMemsetAsync(bcount, 0, 2048, stream);

    int GB = (n + 127) / 128;
    int NBH = 1024;
    gemm_hist<<<GB + NBH, 256, 0, stream>>>(x, W, att_src, att_dst, h, a_src, a_dst, n,
                                            ei, bcount, E, sh, GB);
    bscatter<<<(E + n + KEDGE - 1) / KEDGE, 256, 0, stream>>>(ei, bcount, gcursor, bkt, E, n, sh);
    bsort<<<NB, 256, 0, stream>>>(bkt, bcount, off, sorted, n, E, sh);
    aggregate<<<2048, 256, 0, stream>>>(h, sorted, off, a_src, a_dst, bias_conv,
                                        W_lin, b_lin, (float*)d_out, n);
}

// Round 12
// 294.636 us; speedup vs baseline: 1.4083x; 1.4083x over previous
//
#include <hip/hip_runtime.h>
#include <hip/hip_fp16.h>
#include <cstdint>
#include <cstddef>

#define NHEADS 4
#define OUT_C 32
#define HC 128          // NHEADS*OUT_C
#define IN_CH 128
#define NEG_SLOPE 0.2f
#define LDSPAD 136      // halves per LDS row (128 + 8 pad)
#define KEDGE 4096      // edges per bscatter block (16/thread)

typedef _Float16 half8 __attribute__((ext_vector_type(8)));
typedef float floatx4 __attribute__((ext_vector_type(4)));

static inline size_t align256(size_t v) { return (v + 255) & ~(size_t)255; }

__device__ __forceinline__ float lrelu(float v) { return v > 0.f ? v : NEG_SLOPE * v; }

__device__ __forceinline__ float wred_sum(float v) {
    v += __shfl_xor(v, 1);
    v += __shfl_xor(v, 2);
    v += __shfl_xor(v, 4);
    v += __shfl_xor(v, 8);
    v += __shfl_xor(v, 16);
    v += __shfl_xor(v, 32);
    return v;
}

__device__ __forceinline__ unsigned int pack_h2(float a, float b) {
    __half2 h = __floats2half2_rn(a, b);
    return *reinterpret_cast<unsigned int*>(&h);
}
__device__ __forceinline__ float2 unpack_h2(unsigned int u) {
    __half2 h = *reinterpret_cast<__half2*>(&u);
    return __half22float2(h);
}

// Block-level int64-vs-int32 edge dtype detect (odd words zero => int64).
__device__ __forceinline__ int detect_f64(const int* __restrict__ ei, int E, int* sf) {
    int t = threadIdx.x;
    if (t == 0) *sf = 0;
    __syncthreads();
    int lim = E < 1024 ? E : 1024;
    int acc = 0;
    for (int i = t; i < lim; i += 256) acc |= ei[2 * i + 1];
    acc |= __shfl_xor(acc, 1);
    acc |= __shfl_xor(acc, 2);
    acc |= __shfl_xor(acc, 4);
    acc |= __shfl_xor(acc, 8);
    acc |= __shfl_xor(acc, 16);
    acc |= __shfl_xor(acc, 32);
    if ((t & 63) == 0 && acc) atomicOr(sf, 1);
    __syncthreads();
    return *sf == 0;
}

// ---------------------------------------------------------------------------
// Fused kernel: blocks [0,GB) run the MFMA GEMM producing h (fp16) + attention
// logits; blocks [GB, GB+NBH) run the bucket histogram (independent work that
// overlaps the MFMA phase's latency bubbles). [measured r11: worth ~36us vs
// separate dispatches]
__global__ __launch_bounds__(256) void gemm_hist(const float* __restrict__ x,
                                                 const float* __restrict__ W,
                                                 const float* __restrict__ att_src,
                                                 const float* __restrict__ att_dst,
                                                 __half* __restrict__ h,
                                                 float* __restrict__ a_src,
                                                 float* __restrict__ a_dst, int n,
                                                 const int* __restrict__ ei,
                                                 int* __restrict__ bcount,
                                                 int E, int sh, int GB) {
    __shared__ __align__(16) _Float16 Ws[128 * LDSPAD];
    __shared__ __align__(16) _Float16 Xs[128 * LDSPAD];   // reused as h-tile
    __shared__ int hc[256];
    __shared__ int sf;
    int tid = threadIdx.x;

    if (blockIdx.x >= GB) {
        // ---------------- bucket histogram part ----------------
        hc[tid] = 0;
        int f64 = detect_f64(ei, E, &sf);   // includes syncthreads
        int nbh = gridDim.x - GB;
        int stride = nbh * 256;
        for (int i = (blockIdx.x - GB) * 256 + tid; i < E; i += stride) {
            int d;
            if (f64) d = (int)((const long long*)ei)[(size_t)E + i];
            else     d = ei[(size_t)E + i];
            atomicAdd(&hc[d >> sh], 1);
        }
        __syncthreads();
        if (hc[tid]) atomicAdd(&bcount[tid], hc[tid]);
        return;
    }
    // ---------------- GEMM part ----------------
    int rowbase = blockIdx.x << 7;

    // stage W with fp32->fp16 conversion (4096 float4)
    const float4* wf = (const float4*)W;
#pragma unroll
    for (int i = 0; i < 16; ++i) {
        int u = (i << 8) + tid;
        int r = u >> 5, g = u & 31;
        float4 v = wf[u];
        uint2 uu;
        uu.x = pack_h2(v.x, v.y);
        uu.y = pack_h2(v.z, v.w);
        *(uint2*)&Ws[r * LDSPAD + (g << 2)] = uu;
    }
    const float4* x4 = (const float4*)x;
#pragma unroll
    for (int i = 0; i < 16; ++i) {
        int u = (i << 8) + tid;
        int r = u >> 5, c4 = u & 31;
        int row = rowbase + r;
        if (row >= n) row = n - 1;
        float4 v = x4[((size_t)row << 5) + c4];
        uint2 uu;
        uu.x = pack_h2(v.x, v.y);
        uu.y = pack_h2(v.z, v.w);
        *(uint2*)&Xs[r * LDSPAD + (c4 << 2)] = uu;
    }
    __syncthreads();

    int lane = tid & 63, w = tid >> 6;
    int quad = lane >> 4, Lm = lane & 15;
    floatx4 acc[2][8];
#pragma unroll
    for (int rt = 0; rt < 2; ++rt)
#pragma unroll
        for (int c = 0; c < 8; ++c) acc[rt][c] = (floatx4){0.f, 0.f, 0.f, 0.f};

#pragma unroll
    for (int kc = 0; kc < 128; kc += 32) {
        int ko = kc + (quad << 3);
        half8 a0 = *(const half8*)&Xs[((w << 5) + Lm) * LDSPAD + ko];
        half8 a1 = *(const half8*)&Xs[((w << 5) + 16 + Lm) * LDSPAD + ko];
#pragma unroll
        for (int c = 0; c < 8; ++c) {
            half8 b = *(const half8*)&Ws[((c << 4) + Lm) * LDSPAD + ko];
            acc[0][c] = __builtin_amdgcn_mfma_f32_16x16x32_f16(a0, b, acc[0][c], 0, 0, 0);
            acc[1][c] = __builtin_amdgcn_mfma_f32_16x16x32_f16(a1, b, acc[1][c], 0, 0, 0);
        }
    }
    __syncthreads();
#pragma unroll
    for (int rt = 0; rt < 2; ++rt)
#pragma unroll
        for (int c = 0; c < 8; ++c)
#pragma unroll
            for (int i = 0; i < 4; ++i) {
                int rl = (w << 5) + (rt << 4) + (quad << 2) + i;
                int cl = (c << 4) + Lm;
                Xs[rl * LDSPAD + cl] = (_Float16)acc[rt][c][i];
            }
    __syncthreads();
    // coalesced interleaved h store
#pragma unroll
    for (int i = 0; i < 8; ++i) {
        int u = (i << 8) + tid;
        int r = u >> 4, g = u & 15;
        int row = rowbase + r;
        if (row < n) {
            uint4 v = *(uint4*)&Xs[r * LDSPAD + (g << 3)];
            *(uint4*)(h + ((size_t)row << 7) + (g << 3)) = v;
        }
    }
    // attention logits: thread covers row r=tid>>1, cols seg*64..+63
    int r = tid >> 1, seg = tid & 1;
    int row = rowbase + r;
    const _Float16* hp = &Xs[r * LDSPAD + (seg << 6)];
    float sa = 0.f, da = 0.f, sb = 0.f, db = 0.f;
#pragma unroll
    for (int g8 = 0; g8 < 8; ++g8) {
        half8 v = *(const half8*)&hp[g8 << 3];
        int co = (seg << 6) + (g8 << 3);
        float4 A1 = *(const float4*)&att_src[co];
        float4 A2 = *(const float4*)&att_src[co + 4];
        float4 D1 = *(const float4*)&att_dst[co];
        float4 D2 = *(const float4*)&att_dst[co + 4];
        float f0 = (float)v[0], f1 = (float)v[1], f2 = (float)v[2], f3 = (float)v[3];
        float f4 = (float)v[4], f5 = (float)v[5], f6 = (float)v[6], f7 = (float)v[7];
        float ts = f0 * A1.x + f1 * A1.y + f2 * A1.z + f3 * A1.w
                 + f4 * A2.x + f5 * A2.y + f6 * A2.z + f7 * A2.w;
        float td = f0 * D1.x + f1 * D1.y + f2 * D1.z + f3 * D1.w
                 + f4 * D2.x + f5 * D2.y + f6 * D2.z + f7 * D2.w;
        if (g8 < 4) { sa += ts; da += td; } else { sb += ts; db += td; }
    }
    if (row < n) {
        int base = (row << 2) + (seg << 1);
        a_src[base] = sa;
        a_src[base + 1] = sb;
        a_dst[base] = da;
        a_dst[base + 1] = db;
    }
}

// ---------------------------------------------------------------------------
// Pass A: bucket scatter with local bucket-base scan. (dst,src) grouped by
// bucket -> single writer block per 64B line.
__global__ __launch_bounds__(256) void bscatter(const int* __restrict__ ei,
                                                const int* __restrict__ bcount,
                                                int* __restrict__ gcursor,
                                                int2* __restrict__ bkt,
                                                int E, int n, int sh) {
    __shared__ int cnt[256], base[256], lcur[256], ts[256];
    __shared__ int sf;
    int t = threadIdx.x;
    cnt[t] = 0;
    lcur[t] = 0;
    int f64 = detect_f64(ei, E, &sf);   // includes syncthreads
    int total = E + n;
    int i0 = blockIdx.x * KEDGE;
    int ed[16], es[16];
#pragma unroll
    for (int j = 0; j < 16; ++j) {
        int i = i0 + (j << 8) + t;
        int s = 0, d = -1;
        if (i < total) {
            if (i < E) {
                if (f64) {
                    s = (int)((const long long*)ei)[i];
                    d = (int)((const long long*)ei)[(size_t)E + i];
                } else {
                    s = ei[i];
                    d = ei[(size_t)E + i];
                }
            } else {
                s = d = i - E;
            }
            atomicAdd(&cnt[d >> sh], 1);
        }
        ed[j] = d;
        es[j] = s;
    }
    // bucket-base scan (bcount + analytic self-loops)
    int lo = t << sh, hi = (t + 1) << sh;
    if (hi > n) hi = n;
    int nodes = hi > lo ? hi - lo : 0;
    int v = bcount[t] + nodes;
    ts[t] = v;
    __syncthreads();
    int run = v;
    for (int d = 1; d < 256; d <<= 1) {
        int o = (t >= d) ? ts[t - d] : 0;
        __syncthreads();
        run += o;
        ts[t] = run;
        __syncthreads();
    }
    int excl = run - v;
    base[t] = excl + (cnt[t] ? atomicAdd(&gcursor[t], cnt[t]) : 0);
    __syncthreads();
#pragma unroll
    for (int j = 0; j < 16; ++j) {
        int d = ed[j];
        if (d >= 0) {
            int b = d >> sh;
            int pos = base[b] + atomicAdd(&lcur[b], 1);
            bkt[pos] = make_int2(d, es[j]);
        }
    }
}

// ---------------------------------------------------------------------------
// Pass B: one block per bucket. Local bucket-base scan, per-node histogram +
// block scan (emits off[]) + in-bucket scatter (L2-local writes).
__global__ __launch_bounds__(256) void bsort(const int2* __restrict__ bkt,
                                             const int* __restrict__ bcount,
                                             int* __restrict__ off,
                                             int* __restrict__ sorted,
                                             int n, int E, int sh) {
    __shared__ int cnt[512], offl[512], ts[256];
    int t = threadIdx.x, bid = blockIdx.x;
    int lo = t << sh, hi = (t + 1) << sh;
    if (hi > n) hi = n;
    int nodes = hi > lo ? hi - lo : 0;
    int v = bcount[t] + nodes;
    ts[t] = v;
    __syncthreads();
    int run = v;
    for (int d = 1; d < 256; d <<= 1) {
        int o = (t >= d) ? ts[t - d] : 0;
        __syncthreads();
        run += o;
        ts[t] = run;
        __syncthreads();
    }
    int e0 = (bid > 0) ? ts[bid - 1] : 0;
    int e1 = ts[bid];
    if (bid == gridDim.x - 1 && t == 0) off[n] = E + n;
    int node0 = bid << sh;
    int node1 = (bid + 1) << sh;
    if (node1 > n) node1 = n;
    int nn = node1 - node0;
    __syncthreads();
    cnt[t] = 0;
    cnt[t + 256] = 0;
    __syncthreads();
    for (int i = e0 + t; i < e1; i += 256) {
        int2 e = bkt[i];
        atomicAdd(&cnt[e.x - node0], 1);
    }
    __syncthreads();
    int a = cnt[t << 1], b = cnt[(t << 1) + 1];
    int s = a + b;
    ts[t] = s;
    __syncthreads();
    run = s;
    for (int d = 1; d < 256; d <<= 1) {
        int o = (t >= d) ? ts[t - d] : 0;
        __syncthreads();
        run += o;
        ts[t] = run;
        __syncthreads();
    }
    int excl = run - s;
    offl[t << 1] = excl;
    offl[(t << 1) + 1] = excl + a;
    cnt[t << 1] = 0;
    cnt[(t << 1) + 1] = 0;
    __syncthreads();
    for (int i = t; i < nn; i += 256) off[node0 + i] = e0 + offl[i];
    for (int i = e0 + t; i < e1; i += 256) {
        int2 e = bkt[i];
        int li = e.x - node0;
        int pos = e0 + offl[li] + atomicAdd(&cnt[li], 1);
        sorted[pos] = e.y;
    }
}

// ---------------------------------------------------------------------------
// Gather-accumulate (fp16 h, interleaved), half-wave owns 128ch: lane L owns
// ch 4L..4L+3 (8B/edge). Edges j = half, half+2, ...; 8 gathers in flight.
__device__ __forceinline__ void accum_half(const int* ssrc, const float* sal,
                                           const __half* __restrict__ h,
                                           int deg, int half, int L, int head,
                                           float4& acc) {
    float4 a0 = {0, 0, 0, 0}, a1 = {0, 0, 0, 0}, a2 = {0, 0, 0, 0}, a3 = {0, 0, 0, 0};
    int j = half;
    for (; j + 14 < deg; j += 16) {
        int s0 = ssrc[j], s1 = ssrc[j + 2], s2 = ssrc[j + 4], s3 = ssrc[j + 6];
        int s4 = ssrc[j + 8], s5 = ssrc[j + 10], s6 = ssrc[j + 12], s7 = ssrc[j + 14];
        float w0 = sal[(j << 2) + head];
        float w1 = sal[((j + 2) << 2) + head];
        float w2 = sal[((j + 4) << 2) + head];
        float w3 = sal[((j + 6) << 2) + head];
        float w4 = sal[((j + 8) << 2) + head];
        float w5 = sal[((j + 10) << 2) + head];
        float w6 = sal[((j + 12) << 2) + head];
        float w7 = sal[((j + 14) << 2) + head];
        uint2 u0 = *(const uint2*)(h + ((size_t)s0 << 7) + (L << 2));
        uint2 u1 = *(const uint2*)(h + ((size_t)s1 << 7) + (L << 2));
        uint2 u2 = *(const uint2*)(h + ((size_t)s2 << 7) + (L << 2));
        uint2 u3 = *(const uint2*)(h + ((size_t)s3 << 7) + (L << 2));
        uint2 u4 = *(const uint2*)(h + ((size_t)s4 << 7) + (L << 2));
        uint2 u5 = *(const uint2*)(h + ((size_t)s5 << 7) + (L << 2));
        uint2 u6 = *(const uint2*)(h + ((size_t)s6 << 7) + (L << 2));
        uint2 u7 = *(const uint2*)(h + ((size_t)s7 << 7) + (L << 2));
        float2 fa, fb;
        fa = unpack_h2(u0.x); fb = unpack_h2(u0.y);
        a0.x = fmaf(w0, fa.x, a0.x); a0.y = fmaf(w0, fa.y, a0.y);
        a0.z = fmaf(w0, fb.x, a0.z); a0.w = fmaf(w0, fb.y, a0.w);
        fa = unpack_h2(u1.x); fb = unpack_h2(u1.y);
        a1.x = fmaf(w1, fa.x, a1.x); a1.y = fmaf(w1, fa.y, a1.y);
        a1.z = fmaf(w1, fb.x, a1.z); a1.w = fmaf(w1, fb.y, a1.w);
        fa = unpack_h2(u2.x); fb = unpack_h2(u2.y);
        a2.x = fmaf(w2, fa.x, a2.x); a2.y = fmaf(w2, fa.y, a2.y);
        a2.z = fmaf(w2, fb.x, a2.z); a2.w = fmaf(w2, fb.y, a2.w);
        fa = unpack_h2(u3.x); fb = unpack_h2(u3.y);
        a3.x = fmaf(w3, fa.x, a3.x); a3.y = fmaf(w3, fa.y, a3.y);
        a3.z = fmaf(w3, fb.x, a3.z); a3.w = fmaf(w3, fb.y, a3.w);
        fa = unpack_h2(u4.x); fb = unpack_h2(u4.y);
        a0.x = fmaf(w4, fa.x, a0.x); a0.y = fmaf(w4, fa.y, a0.y);
        a0.z = fmaf(w4, fb.x, a0.z); a0.w = fmaf(w4, fb.y, a0.w);
        fa = unpack_h2(u5.x); fb = unpack_h2(u5.y);
        a1.x = fmaf(w5, fa.x, a1.x); a1.y = fmaf(w5, fa.y, a1.y);
        a1.z = fmaf(w5, fb.x, a1.z); a1.w = fmaf(w5, fb.y, a1.w);
        fa = unpack_h2(u6.x); fb = unpack_h2(u6.y);
        a2.x = fmaf(w6, fa.x, a2.x); a2.y = fmaf(w6, fa.y, a2.y);
        a2.z = fmaf(w6, fb.x, a2.z); a2.w = fmaf(w6, fb.y, a2.w);
        fa = unpack_h2(u7.x); fb = unpack_h2(u7.y);
        a3.x = fmaf(w7, fa.x, a3.x); a3.y = fmaf(w7, fa.y, a3.y);
        a3.z = fmaf(w7, fb.x, a3.z); a3.w = fmaf(w7, fb.y, a3.w);
    }
    for (; j + 6 < deg; j += 8) {
        int s0 = ssrc[j], s1 = ssrc[j + 2], s2 = ssrc[j + 4], s3 = ssrc[j + 6];
        float w0 = sal[(j << 2) + head];
        float w1 = sal[((j + 2) << 2) + head];
        float w2 = sal[((j + 4) << 2) + head];
        float w3 = sal[((j + 6) << 2) + head];
        uint2 u0 = *(const uint2*)(h + ((size_t)s0 << 7) + (L << 2));
        uint2 u1 = *(const uint2*)(h + ((size_t)s1 << 7) + (L << 2));
        uint2 u2 = *(const uint2*)(h + ((size_t)s2 << 7) + (L << 2));
        uint2 u3 = *(const uint2*)(h + ((size_t)s3 << 7) + (L << 2));
        float2 fa, fb;
        fa = unpack_h2(u0.x); fb = unpack_h2(u0.y);
        a0.x = fmaf(w0, fa.x, a0.x); a0.y = fmaf(w0, fa.y, a0.y);
        a0.z = fmaf(w0, fb.x, a0.z); a0.w = fmaf(w0, fb.y, a0.w);
        fa = unpack_h2(u1.x); fb = unpack_h2(u1.y);
        a1.x = fmaf(w1, fa.x, a1.x); a1.y = fmaf(w1, fa.y, a1.y);
        a1.z = fmaf(w1, fb.x, a1.z); a1.w = fmaf(w1, fb.y, a1.w);
        fa = unpack_h2(u2.x); fb = unpack_h2(u2.y);
        a2.x = fmaf(w2, fa.x, a2.x); a2.y = fmaf(w2, fa.y, a2.y);
        a2.z = fmaf(w2, fb.x, a2.z); a2.w = fmaf(w2, fb.y, a2.w);
        fa = unpack_h2(u3.x); fb = unpack_h2(u3.y);
        a3.x = fmaf(w3, fa.x, a3.x); a3.y = fmaf(w3, fa.y, a3.y);
        a3.z = fmaf(w3, fb.x, a3.z); a3.w = fmaf(w3, fb.y, a3.w);
    }
    for (; j < deg; j += 2) {
        int s0 = ssrc[j];
        float w0 = sal[(j << 2) + head];
        uint2 u0 = *(const uint2*)(h + ((size_t)s0 << 7) + (L << 2));
        float2 fa = unpack_h2(u0.x), fb = unpack_h2(u0.y);
        a0.x = fmaf(w0, fa.x, a0.x); a0.y = fmaf(w0, fa.y, a0.y);
        a0.z = fmaf(w0, fb.x, a0.z); a0.w = fmaf(w0, fb.y, a0.w);
    }
    acc.x += (a0.x + a1.x) + (a2.x + a3.x);
    acc.y += (a0.y + a1.y) + (a2.y + a3.y);
    acc.z += (a0.z + a1.z) + (a2.z + a3.z);
    acc.w += (a0.w + a1.w) + (a2.w + a3.w);
}

// One wave per destination node. Staging: lane-per-edge src read + a_src
// gather + alpha=exp(lrelu(.)) fp32 -> LDS. Normalization in epilogue.
// NOTE (r11): do NOT fuse proj here -- any serial per-node epilogue work
// deflates the per-CU outstanding-miss count and collapses gather BW.
__global__ __launch_bounds__(256) void aggregate(const __half* __restrict__ h,
                                                 const int* __restrict__ sorted,
                                                 const int* __restrict__ off,
                                                 const float* __restrict__ a_src,
                                                 const float* __restrict__ a_dst,
                                                 const float* __restrict__ bias,
                                                 __half* __restrict__ agg, int n) {
    __shared__ __align__(16) int sh_src[4][64];
    __shared__ __align__(16) float sh_al[4][256];    // [edge][head]
    int wslot = threadIdx.x >> 6;
    int lane = threadIdx.x & 63;
    int wid = blockIdx.x * 4 + wslot;
    int nw = gridDim.x * 4;
    int L = lane & 31, half = lane >> 5, head = L >> 3;
    float4 b4 = ((const float4*)bias)[L];
    const float4* as4 = (const float4*)a_src;
    const float4* ad4 = (const float4*)a_dst;
    int* ssrc = sh_src[wslot];
    float* sal = sh_al[wslot];

    for (int node = wid; node < n; node += nw) {
        int start = off[node], end = off[node + 1];
        int deg = end - start;          // >= 1 (self loop)
        float4 ad = ad4[node];
        float4 acc = {0.f, 0.f, 0.f, 0.f};
        float4 psum = {0.f, 0.f, 0.f, 0.f};

        if (deg <= 64) {
            bool v = lane < deg;
            int idx = start + (v ? lane : 0);
            int s = sorted[idx];
            float4 as = as4[s];
            float4 p;
            p.x = v ? __expf(lrelu(as.x + ad.x)) : 0.f;
            p.y = v ? __expf(lrelu(as.y + ad.y)) : 0.f;
            p.z = v ? __expf(lrelu(as.z + ad.z)) : 0.f;
            p.w = v ? __expf(lrelu(as.w + ad.w)) : 0.f;
            psum = p;
            ssrc[lane] = s;
            *(float4*)&sal[lane << 2] = p;
            asm volatile("s_waitcnt lgkmcnt(0)" ::: "memory");
            accum_half(ssrc, sal, h, deg, half, L, head, acc);
            asm volatile("" ::: "memory");
        } else {
            // chunked path (rare)
            for (int bb = 0; bb < deg; bb += 64) {
                int i = bb + lane;
                bool v = i < deg;
                int idx = start + (v ? i : 0);
                int s = sorted[idx];
                float4 as = as4[s];
                float4 p;
                p.x = v ? __expf(lrelu(as.x + ad.x)) : 0.f;
                p.y = v ? __expf(lrelu(as.y + ad.y)) : 0.f;
                p.z = v ? __expf(lrelu(as.z + ad.z)) : 0.f;
                p.w = v ? __expf(lrelu(as.w + ad.w)) : 0.f;
                psum.x += p.x; psum.y += p.y; psum.z += p.z; psum.w += p.w;
                ssrc[lane] = s;
                *(float4*)&sal[lane << 2] = p;
                asm volatile("s_waitcnt lgkmcnt(0)" ::: "memory");
                int cl = deg - bb;
                if (cl > 64) cl = 64;
                accum_half(ssrc, sal, h, cl, half, L, head, acc);
                asm volatile("" ::: "memory");
            }
        }
        float s0 = wred_sum(psum.x), s1 = wred_sum(psum.y);
        float s2 = wred_sum(psum.z), s3 = wred_sum(psum.w);
        float sh = (head == 0) ? s0 : (head == 1) ? s1 : (head == 2) ? s2 : s3;
        float inv = 1.f / sh;
        acc.x += __shfl_xor(acc.x, 32);
        acc.y += __shfl_xor(acc.y, 32);
        acc.z += __shfl_xor(acc.z, 32);
        acc.w += __shfl_xor(acc.w, 32);
        if (lane < 32) {
            float4 res = {fmaf(acc.x, inv, b4.x), fmaf(acc.y, inv, b4.y),
                          fmaf(acc.z, inv, b4.z), fmaf(acc.w, inv, b4.w)};
            uint2 u;
            u.x = pack_h2(res.x, res.y);
            u.y = pack_h2(res.z, res.w);
            *(uint2*)(agg + ((size_t)node << 7) + (L << 2)) = u;
        }
    }
}

// ---------------------------------------------------------------------------
// out[n][32] = elu(agg[n][128] (fp16) @ W_lin^T + b_lin)
__global__ __launch_bounds__(256) void proj(const __half* __restrict__ agg,
                                            const float* __restrict__ W_lin,
                                            const float* __restrict__ b_lin,
                                            float* __restrict__ out, int n) {
    __shared__ float xs[64][132];
    __shared__ float wt[128][36];   // wt[k][o]
    int tid = threadIdx.x;
    const float4* w4 = (const float4*)W_lin;
#pragma unroll
    for (int i = 0; i < 4; ++i) {
        int f4 = (i << 8) + tid;          // 0..1023
        int o = f4 >> 5, kk = (f4 & 31) << 2;
        float4 w = w4[f4];
        wt[kk][o] = w.x;
        wt[kk + 1][o] = w.y;
        wt[kk + 2][o] = w.z;
        wt[kk + 3][o] = w.w;
    }
    int rowbase = blockIdx.x << 6;
    const uint4* a4 = (const uint4*)agg;   // 8 halves per uint4; 16 per row
#pragma unroll
    for (int i = 0; i < 4; ++i) {
        int f8 = (i << 8) + tid;          // 0..1023
        int r = f8 >> 4, cc = (f8 & 15) << 3;
        int row = rowbase + r;
        if (row >= n) row = n - 1;
        uint4 u = a4[((size_t)row << 4) + (cc >> 3)];
        float2 f0 = unpack_h2(u.x), f1 = unpack_h2(u.y);
        float2 f2 = unpack_h2(u.z), f3 = unpack_h2(u.w);
        float* xp = &xs[r][cc];
        xp[0] = f0.x; xp[1] = f0.y; xp[2] = f1.x; xp[3] = f1.y;
        xp[4] = f2.x; xp[5] = f2.y; xp[6] = f3.x; xp[7] = f3.y;
    }
    __syncthreads();
    int r = tid >> 2, cg = tid & 3, c0 = cg << 3;
    float acc[8];
#pragma unroll
    for (int j = 0; j < 8; ++j) acc[j] = 0.f;
    for (int k = 0; k < 128; k += 4) {
        float4 xv = *(const float4*)&xs[r][k];
        float xk[4] = {xv.x, xv.y, xv.z, xv.w};
#pragma unroll
        for (int kk = 0; kk < 4; ++kk) {
            float4 wa = *(const float4*)&wt[k + kk][c0];
            float4 wb = *(const float4*)&wt[k + kk][c0 + 4];
            acc[0] = fmaf(xk[kk], wa.x, acc[0]);
            acc[1] = fmaf(xk[kk], wa.y, acc[1]);
            acc[2] = fmaf(xk[kk], wa.z, acc[2]);
            acc[3] = fmaf(xk[kk], wa.w, acc[3]);
            acc[4] = fmaf(xk[kk], wb.x, acc[4]);
            acc[5] = fmaf(xk[kk], wb.y, acc[5]);
            acc[6] = fmaf(xk[kk], wb.z, acc[6]);
            acc[7] = fmaf(xk[kk], wb.w, acc[7]);
        }
    }
    int row = rowbase + r;
    if (row < n) {
        float res[8];
#pragma unroll
        for (int j = 0; j < 8; ++j) {
            float v = acc[j] + b_lin[c0 + j];
            res[j] = v > 0.f ? v : (__expf(v) - 1.f);
        }
        float4* op = (float4*)(out + (size_t)row * 32 + c0);
        op[0] = make_float4(res[0], res[1], res[2], res[3]);
        op[1] = make_float4(res[4], res[5], res[6], res[7]);
    }
}

// ---------------------------------------------------------------------------
extern "C" void kernel_launch(void* const* d_in, const int* in_sizes, int n_in,
                              void* d_out, int out_size, void* d_ws, size_t ws_size,
                              hipStream_t stream) {
    const float* x = (const float*)d_in[0];
    const int* ei = (const int*)d_in[1];
    const float* W = (const float*)d_in[2];
    const float* att_src = (const float*)d_in[3];
    const float* att_dst = (const float*)d_in[4];
    const float* bias_conv = (const float*)d_in[5];
    const float* W_lin = (const float*)d_in[6];
    const float* b_lin = (const float*)d_in[7];
    int n = in_sizes[0] / IN_CH;
    int E = in_sizes[1] / 2;

    int sh = 0;
    while (((n + (1 << sh) - 1) >> sh) > 256) sh++;
    int NB = (n + (1 << sh) - 1) >> sh;

    char* ws = (char*)d_ws;
    size_t o = 0;
    auto alloc = [&](size_t bytes) { char* p = ws + o; o = align256(o + bytes); return p; };
    __half* h      = (__half*)alloc((size_t)n * HC * 2);
    __half* agg    = (__half*)alloc((size_t)n * HC * 2);
    float* a_src   = (float*)alloc((size_t)n * NHEADS * 4);
    float* a_dst   = (float*)alloc((size_t)n * NHEADS * 4);
    int* off       = (int*)alloc(((size_t)n + 1) * 4);
    int* bcount    = (int*)alloc(256 * 4);
    int* gcursor   = (int*)alloc(256 * 4);
    int* sorted    = (int*)alloc((size_t)(E + n + 64) * 4);
    int2* bkt      = (int2*)alloc((size_t)(E + n + 64) * 8);

    // bcount and gcursor are adjacent: one memset covers both
    hipMemsetAsync(bcount, 0, 2048, stream);

    int GB = (n + 127) / 128;
    int NBH = 1024;
    gemm_hist<<<GB + NBH, 256, 0, stream>>>(x, W, att_src, att_dst, h, a_src, a_dst, n,
                                            ei, bcount, E, sh, GB);
    bscatter<<<(E + n + KEDGE - 1) / KEDGE, 256, 0, stream>>>(ei, bcount, gcursor, bkt, E, n, sh);
    bsort<<<NB, 256, 0, stream>>>(bkt, bcount, off, sorted, n, E, sh);
    aggregate<<<2048, 256, 0, stream>>>(h, sorted, off, a_src, a_dst, bias_conv, agg, n);
    proj<<<(n + 63) / 64, 256, 0, stream>>>(agg, W_lin, b_lin, (float*)d_out, n);
}